// Round 1
// baseline (551.082 us; speedup 1.0000x reference)
//
#include <hip/hip_runtime.h>

typedef __attribute__((ext_vector_type(4))) float f32x4;
typedef __attribute__((ext_vector_type(8))) short bf16x8;
typedef __attribute__((ext_vector_type(4))) unsigned short u16x4;
typedef unsigned short u16;

#define DM 1024
#define NHEAD 16
#define DHEAD 64
#define QLEN 2048
#define MLEN 2048
#define KLEN 4096

__device__ __forceinline__ float bf2f(u16 u) {
    unsigned i = ((unsigned)u) << 16; float f; __builtin_memcpy(&f, &i, 4); return f;
}
__device__ __forceinline__ u16 f2bf(float f) {
    unsigned i; __builtin_memcpy(&i, &f, 4);
    unsigned r = i + 0x7fffu + ((i >> 16) & 1u);
    return (u16)(r >> 16);
}
__device__ __forceinline__ void gl2lds16(const void* g, void* l) {
    __builtin_amdgcn_global_load_lds((const __attribute__((address_space(1))) void*)g,
                                     (__attribute__((address_space(3))) void*)l, 16, 0, 0);
}

// ---------------- pack: memory||hidden -> bf16, pos -> bf16 ----------------
__global__ __launch_bounds__(256) void pack_inputs(
    const float* __restrict__ memory, const float* __restrict__ hidden,
    const float* __restrict__ pos, u16* __restrict__ MH, u16* __restrict__ PEA)
{
    size_t idx = (size_t)blockIdx.x * 256 + threadIdx.x;
    size_t e = idx * 4;
    const size_t HALF = (size_t)KLEN * DM;
    f32x4 v; u16* dst;
    if (e < HALF) {
        size_t row = e >> 10, col = e & 1023;
        const float* src = (row < MLEN) ? (memory + row * DM) : (hidden + (row - MLEN) * DM);
        v = *(const f32x4*)(src + col);
        dst = MH + e;
    } else {
        size_t e2 = e - HALF;
        v = *(const f32x4*)(pos + e2);
        dst = PEA + e2;
    }
    u16x4 o;
    #pragma unroll
    for (int c = 0; c < 4; ++c) o[c] = f2bf(v[c]);
    *(u16x4*)dst = o;
}

// ---------------- transpose f32 (K x N) -> bf16 (N x K) ----------------
__global__ __launch_bounds__(256) void transpose_w(
    const float* __restrict__ src, u16* __restrict__ dst, int K, int N)
{
    __shared__ float ls[64][65];
    const int n0 = blockIdx.x * 64, k0 = blockIdx.y * 64;
    const int t = threadIdx.x, c = t & 63, rg = t >> 6;
    #pragma unroll
    for (int p = 0; p < 16; ++p) {
        int r = p * 4 + rg;
        ls[r][c] = src[(size_t)(k0 + r) * N + n0 + c];
    }
    __syncthreads();
    #pragma unroll
    for (int p = 0; p < 16; ++p) {
        int r = p * 4 + rg;
        dst[(size_t)(n0 + r) * K + k0 + c] = f2bf(ls[c][r]);
    }
}

// ---------------- GEMM: C(MxN) = A(MxK,bf16) * Bt(NxK,bf16)^T ----------------
// ADD_RES=0: write bf16 C.  ADD_RES=1: write f32 C = acc + addend.
template<int ADD_RES>
__global__ __launch_bounds__(256, 2) void gemm_bt(
    const u16* __restrict__ A, const u16* __restrict__ Bt,
    u16* __restrict__ Cb, float* __restrict__ Cf, const float* __restrict__ addend,
    int M, int N, int K)
{
    __shared__ u16 lsA[128 * 64];
    __shared__ u16 lsB[128 * 64];
    const int row0 = blockIdx.x * 128, col0 = blockIdx.y * 128;
    const int tid = threadIdx.x, wave = tid >> 6, lane = tid & 63;
    const int blk = lane >> 4, ln = lane & 15;
    const int wr = (wave >> 1) << 6, wc = (wave & 1) << 6;
    const int rstage = lane >> 3;          // 0..7 rows within 8-row chunk
    const int cstage = (lane & 7) * 8;     // bf16 col within 64

    f32x4 acc[4][4];
    #pragma unroll
    for (int i = 0; i < 4; ++i)
        #pragma unroll
        for (int j = 0; j < 4; ++j) acc[i][j] = f32x4{0.f, 0.f, 0.f, 0.f};

    for (int k0 = 0; k0 < K; k0 += 64) {
        #pragma unroll
        for (int t = 0; t < 4; ++t) {
            int chunk = wave * 4 + t;          // 0..15 -> rows chunk*8..+7
            int r = chunk * 8 + rstage;
            gl2lds16(A  + (size_t)(row0 + r) * K + k0 + cstage, lsA + chunk * 512);
            gl2lds16(Bt + (size_t)(col0 + r) * K + k0 + cstage, lsB + chunk * 512);
        }
        __syncthreads();
        #pragma unroll
        for (int kk = 0; kk < 2; ++kk) {
            bf16x8 af[4], bfr[4];
            #pragma unroll
            for (int i = 0; i < 4; ++i)
                af[i] = *(const bf16x8*)(lsA + (wr + i * 16 + ln) * 64 + kk * 32 + blk * 8);
            #pragma unroll
            for (int j = 0; j < 4; ++j)
                bfr[j] = *(const bf16x8*)(lsB + (wc + j * 16 + ln) * 64 + kk * 32 + blk * 8);
            #pragma unroll
            for (int i = 0; i < 4; ++i)
                #pragma unroll
                for (int j = 0; j < 4; ++j)
                    acc[i][j] = __builtin_amdgcn_mfma_f32_16x16x32_bf16(af[i], bfr[j], acc[i][j], 0, 0, 0);
        }
        __syncthreads();
    }
    #pragma unroll
    for (int i = 0; i < 4; ++i)
        #pragma unroll
        for (int j = 0; j < 4; ++j)
            #pragma unroll
            for (int r = 0; r < 4; ++r) {
                int row = row0 + wr + i * 16 + blk * 4 + r;
                int col = col0 + wc + j * 16 + ln;
                float v = acc[i][j][r];
                if (ADD_RES) {
                    Cf[(size_t)row * N + col] = v + addend[(size_t)row * N + col];
                } else {
                    Cb[(size_t)row * N + col] = f2bf(v);
                }
            }
}

// ---------------- pack QHAT / KHAT ----------------
// QHAT[h][q][0:64] = (Q+u)*0.125, [64:128] = (Q+v)*0.125   (scale folded in)
// KHAT[h][k][0:64] = K, [64:128] = pe
__global__ __launch_bounds__(256) void pack_qk(
    const u16* __restrict__ QKVb, const u16* __restrict__ PEb,
    const float* __restrict__ u, const float* __restrict__ v,
    u16* __restrict__ QHAT, u16* __restrict__ KHAT)
{
    size_t idx = (size_t)blockIdx.x * 256 + threadIdx.x;
    const size_t QPART = (size_t)NHEAD * QLEN * DHEAD;   // 1<<21
    if (idx < QPART) {
        int d = idx & 63;
        int q = (idx >> 6) & (QLEN - 1);
        int h = idx >> 17;
        float qv = bf2f(QKVb[(size_t)(MLEN + q) * (3 * DM) + h * 64 + d]);
        QHAT[((size_t)h * QLEN + q) * 128 + d]      = f2bf((qv + u[h * 64 + d]) * 0.125f);
        QHAT[((size_t)h * QLEN + q) * 128 + 64 + d] = f2bf((qv + v[h * 64 + d]) * 0.125f);
    } else {
        size_t j = idx - QPART;
        int d = j & 63;
        int k = (j >> 6) & (KLEN - 1);
        int h = j >> 18;
        KHAT[((size_t)h * KLEN + k) * 128 + d]      = QKVb[(size_t)k * (3 * DM) + DM + h * 64 + d];
        KHAT[((size_t)h * KLEN + k) * 128 + 64 + d] = PEb[(size_t)k * DM + h * 64 + d];
    }
}

// ---------------- pack VT[h][d][k] = V[k][h][d] ----------------
__global__ __launch_bounds__(256) void pack_vt(const u16* __restrict__ QKVb, u16* __restrict__ VT)
{
    __shared__ float ls[64][65];
    const int kt = blockIdx.x, h = blockIdx.y;
    const int t = threadIdx.x, c = t & 63, rg = t >> 6;
    #pragma unroll
    for (int p = 0; p < 16; ++p) {
        int r = p * 4 + rg;
        ls[r][c] = bf2f(QKVb[(size_t)(kt * 64 + r) * (3 * DM) + 2 * DM + h * 64 + c]);
    }
    __syncthreads();
    #pragma unroll
    for (int p = 0; p < 16; ++p) {
        int d = p * 4 + rg;
        VT[((size_t)h * DHEAD + d) * KLEN + kt * 64 + c] = f2bf(ls[c][d]);
    }
}

// ---------------- fused flash attention ----------------
// grid (QLEN/64, NHEAD), 4 waves, each wave owns 16 q-rows independently.
__global__ __launch_bounds__(256) void attn_fused(
    const u16* __restrict__ QHAT, const u16* __restrict__ KHAT,
    const u16* __restrict__ VT, u16* __restrict__ AVB)
{
    __shared__ u16 pbuf[4][16 * 64];
    const int h = blockIdx.y, qb = blockIdx.x;
    const int wave = threadIdx.x >> 6, lane = threadIdx.x & 63;
    const int blk = lane >> 4, ln = lane & 15;
    const int qrow0 = qb * 64 + wave * 16;
    u16* pb = pbuf[wave];

    // Q' fragments: rows = qrow0 + ln, k-dim chunks of 32 (consistent myk for A & B)
    bf16x8 qf[4];
    const u16* qbase = QHAT + ((size_t)h * QLEN + qrow0 + ln) * 128;
    #pragma unroll
    for (int c = 0; c < 4; ++c) qf[c] = *(const bf16x8*)(qbase + c * 32 + blk * 8);

    f32x4 oacc[4];
    #pragma unroll
    for (int n = 0; n < 4; ++n) oacc[n] = f32x4{0.f, 0.f, 0.f, 0.f};
    float mi[4], li[4];
    #pragma unroll
    for (int r = 0; r < 4; ++r) { mi[r] = -1e30f; li[r] = 0.f; }

    const int nt = ((qrow0 + 15 + MLEN) >> 6) + 1;
    const u16* kh = KHAT + (size_t)h * KLEN * 128;
    const u16* vh = VT + (size_t)h * DHEAD * KLEN;

    for (int kt = 0; kt < nt; ++kt) {
        const int k0 = kt * 64;
        f32x4 s[4];
        #pragma unroll
        for (int n = 0; n < 4; ++n) s[n] = f32x4{0.f, 0.f, 0.f, 0.f};
        #pragma unroll
        for (int n = 0; n < 4; ++n) {
            const u16* kb = kh + (size_t)(k0 + n * 16 + ln) * 128;
            #pragma unroll
            for (int c = 0; c < 4; ++c) {
                bf16x8 kf = *(const bf16x8*)(kb + c * 32 + blk * 8);
                s[n] = __builtin_amdgcn_mfma_f32_16x16x32_bf16(qf[c], kf, s[n], 0, 0, 0);
            }
        }
        // causal mask: key j allowed iff j <= q + MLEN  (wave-uniform skip when safe)
        if (k0 + 63 > qrow0 + MLEN) {
            #pragma unroll
            for (int n = 0; n < 4; ++n)
                #pragma unroll
                for (int r = 0; r < 4; ++r) {
                    int key = k0 + n * 16 + ln;
                    int q = qrow0 + blk * 4 + r;
                    if (key > q + MLEN) s[n][r] = -1e30f;
                }
        }
        // online softmax (row = blk*4+r lives in the 16 lanes of this blk group)
        #pragma unroll
        for (int r = 0; r < 4; ++r) {
            float mt = fmaxf(fmaxf(s[0][r], s[1][r]), fmaxf(s[2][r], s[3][r]));
            #pragma unroll
            for (int off = 1; off < 16; off <<= 1) mt = fmaxf(mt, __shfl_xor(mt, off, 64));
            float mn = fmaxf(mi[r], mt);
            float corr = __expf(mi[r] - mn);
            mi[r] = mn;
            float rs = 0.f;
            #pragma unroll
            for (int n = 0; n < 4; ++n) { float p = __expf(s[n][r] - mn); s[n][r] = p; rs += p; }
            #pragma unroll
            for (int off = 1; off < 16; off <<= 1) rs += __shfl_xor(rs, off, 64);
            li[r] = li[r] * corr + rs;
            #pragma unroll
            for (int n = 0; n < 4; ++n) oacc[n][r] *= corr;
        }
        // P -> LDS (bf16, XOR-swizzled to kill the 128B-row bank conflict)
        #pragma unroll
        for (int n = 0; n < 4; ++n)
            #pragma unroll
            for (int r = 0; r < 4; ++r) {
                int row = blk * 4 + r, col = n * 16 + ln;
                int a = ((row << 6) | col) << 1;
                a ^= (row & 7) << 4;
                *(u16*)((char*)pb + a) = f2bf(s[n][r]);
            }
        asm volatile("s_waitcnt lgkmcnt(0)" ::: "memory");
        // PV: A = P[q=ln][key], B = VT[d = n*16+ln][key] -- same key permutation
        #pragma unroll
        for (int kk = 0; kk < 2; ++kk) {
            int a = ln * 128 + kk * 64 + blk * 16;
            a ^= (ln & 7) << 4;
            bf16x8 pf = *(const bf16x8*)((char*)pb + a);
            #pragma unroll
            for (int n = 0; n < 4; ++n) {
                bf16x8 vf = *(const bf16x8*)(vh + (size_t)(n * 16 + ln) * KLEN + k0 + kk * 32 + blk * 8);
                oacc[n] = __builtin_amdgcn_mfma_f32_16x16x32_bf16(pf, vf, oacc[n], 0, 0, 0);
            }
        }
    }
    #pragma unroll
    for (int n = 0; n < 4; ++n)
        #pragma unroll
        for (int r = 0; r < 4; ++r) {
            int row = qrow0 + blk * 4 + r;
            int col = h * 64 + n * 16 + ln;
            AVB[(size_t)row * DM + col] = f2bf(oacc[n][r] / li[r]);
        }
}

// ---------------- layernorm over last dim (1024) ----------------
__global__ __launch_bounds__(256) void ln_kernel(const float* __restrict__ RES, float* __restrict__ out)
{
    const int row = blockIdx.x, t = threadIdx.x;
    const int wave = t >> 6, lane = t & 63;
    __shared__ float ws[8];
    f32x4 v = ((const f32x4*)(RES + (size_t)row * DM))[t];
    float s = v[0] + v[1] + v[2] + v[3];
    float s2 = v[0] * v[0] + v[1] * v[1] + v[2] * v[2] + v[3] * v[3];
    #pragma unroll
    for (int off = 1; off < 64; off <<= 1) {
        s += __shfl_xor(s, off, 64);
        s2 += __shfl_xor(s2, off, 64);
    }
    if (lane == 0) { ws[wave] = s; ws[4 + wave] = s2; }
    __syncthreads();
    float ts = ws[0] + ws[1] + ws[2] + ws[3];
    float ts2 = ws[4] + ws[5] + ws[6] + ws[7];
    float mu = ts * (1.f / DM);
    float var = ts2 * (1.f / DM) - mu * mu;
    float rsq = rsqrtf(var + 1e-5f);
    f32x4 o;
    #pragma unroll
    for (int c = 0; c < 4; ++c) o[c] = (v[c] - mu) * rsq;
    ((f32x4*)(out + (size_t)row * DM))[t] = o;
}

extern "C" void kernel_launch(void* const* d_in, const int* in_sizes, int n_in,
                              void* d_out, int out_size, void* d_ws, size_t ws_size,
                              hipStream_t stream)
{
    const float* hidden = (const float*)d_in[0];
    const float* pos    = (const float*)d_in[1];
    const float* u      = (const float*)d_in[2];
    const float* vv     = (const float*)d_in[3];
    // d_in[4] = mask: computed analytically, unused
    const float* memory = (const float*)d_in[5];
    const float* Wqkv   = (const float*)d_in[6];
    const float* Wpe    = (const float*)d_in[7];
    const float* Wout   = (const float*)d_in[8];
    float* out = (float*)d_out;

    char* w = (char*)d_ws;
    auto alloc = [&](size_t bytes) {
        void* p = (void*)w;
        w += (bytes + 255) & ~(size_t)255;
        return p;
    };
    u16* MH    = (u16*)alloc((size_t)KLEN * DM * 2);          // 8 MB
    u16* PEA   = (u16*)alloc((size_t)KLEN * DM * 2);          // 8 MB
    u16* WQKVT = (u16*)alloc((size_t)3 * DM * DM * 2);        // 6 MB
    u16* WPET  = (u16*)alloc((size_t)DM * DM * 2);            // 2 MB
    u16* WOUTT = (u16*)alloc((size_t)DM * DM * 2);            // 2 MB
    u16* QKVb  = (u16*)alloc((size_t)KLEN * 3 * DM * 2);      // 24 MB
    u16* PEb   = (u16*)alloc((size_t)KLEN * DM * 2);          // 8 MB
    u16* QHAT  = (u16*)alloc((size_t)NHEAD * QLEN * 128 * 2); // 8 MB
    u16* KHAT  = (u16*)alloc((size_t)NHEAD * KLEN * 128 * 2); // 16 MB
    u16* VTb   = (u16*)alloc((size_t)NHEAD * DHEAD * KLEN * 2); // 8 MB
    u16* AVB   = (u16*)alloc((size_t)QLEN * DM * 2);          // 4 MB
    float* RES = (float*)alloc((size_t)QLEN * DM * 4);        // 8 MB

    pack_inputs<<<8192, 256, 0, stream>>>(memory, hidden, pos, MH, PEA);
    transpose_w<<<dim3(3 * DM / 64, DM / 64), 256, 0, stream>>>(Wqkv, WQKVT, DM, 3 * DM);
    transpose_w<<<dim3(DM / 64, DM / 64), 256, 0, stream>>>(Wpe, WPET, DM, DM);
    transpose_w<<<dim3(DM / 64, DM / 64), 256, 0, stream>>>(Wout, WOUTT, DM, DM);

    gemm_bt<0><<<dim3(KLEN / 128, 3 * DM / 128), 256, 0, stream>>>(
        MH, WQKVT, QKVb, nullptr, nullptr, KLEN, 3 * DM, DM);
    gemm_bt<0><<<dim3(KLEN / 128, DM / 128), 256, 0, stream>>>(
        PEA, WPET, PEb, nullptr, nullptr, KLEN, DM, DM);

    pack_qk<<<(3u << 21) / 256, 256, 0, stream>>>(QKVb, PEb, u, vv, QHAT, KHAT);
    pack_vt<<<dim3(KLEN / 64, NHEAD), 256, 0, stream>>>(QKVb, VTb);

    attn_fused<<<dim3(QLEN / 64, NHEAD), 256, 0, stream>>>(QHAT, KHAT, VTb, AVB);

    gemm_bt<1><<<dim3(QLEN / 128, DM / 128), 256, 0, stream>>>(
        AVB, WOUTT, nullptr, RES, hidden, QLEN, DM, DM);
    ln_kernel<<<QLEN, 256, 0, stream>>>(RES, out);
}

// Round 2
// 259.597 us; speedup vs baseline: 2.1228x; 2.1228x over previous
//
#include <hip/hip_runtime.h>

typedef __attribute__((ext_vector_type(4))) float f32x4;
typedef __attribute__((ext_vector_type(8))) short bf16x8;
typedef __attribute__((ext_vector_type(4))) unsigned short u16x4;
typedef unsigned short u16;

#define DM 1024
#define NHEAD 16
#define DHEAD 64
#define QLEN 2048
#define MLEN 2048
#define KLEN 4096

__device__ __forceinline__ float bf2f(u16 u) {
    unsigned i = ((unsigned)u) << 16; float f; __builtin_memcpy(&f, &i, 4); return f;
}
__device__ __forceinline__ u16 f2bf(float f) {
    unsigned i; __builtin_memcpy(&i, &f, 4);
    unsigned r = i + 0x7fffu + ((i >> 16) & 1u);
    return (u16)(r >> 16);
}
__device__ __forceinline__ void gl2lds16(const void* g, void* l) {
    __builtin_amdgcn_global_load_lds((const __attribute__((address_space(1))) void*)g,
                                     (__attribute__((address_space(3))) void*)l, 16, 0, 0);
}

// ---------------- pack: memory||hidden -> bf16, pos -> bf16 ----------------
__global__ __launch_bounds__(256) void pack_inputs(
    const float* __restrict__ memory, const float* __restrict__ hidden,
    const float* __restrict__ pos, u16* __restrict__ MH, u16* __restrict__ PEA)
{
    size_t idx = (size_t)blockIdx.x * 256 + threadIdx.x;
    size_t e = idx * 4;
    const size_t HALF = (size_t)KLEN * DM;
    f32x4 v; u16* dst;
    if (e < HALF) {
        size_t row = e >> 10, col = e & 1023;
        const float* src = (row < MLEN) ? (memory + row * DM) : (hidden + (row - MLEN) * DM);
        v = *(const f32x4*)(src + col);
        dst = MH + e;
    } else {
        size_t e2 = e - HALF;
        v = *(const f32x4*)(pos + e2);
        dst = PEA + e2;
    }
    u16x4 o;
    #pragma unroll
    for (int c = 0; c < 4; ++c) o[c] = f2bf(v[c]);
    *(u16x4*)dst = o;
}

// ---------------- transpose f32 (K x N) -> bf16 (N x K) ----------------
__global__ __launch_bounds__(256) void transpose_w(
    const float* __restrict__ src, u16* __restrict__ dst, int K, int N)
{
    __shared__ float ls[64][65];
    const int n0 = blockIdx.x * 64, k0 = blockIdx.y * 64;
    const int t = threadIdx.x, c = t & 63, rg = t >> 6;
    #pragma unroll
    for (int p = 0; p < 16; ++p) {
        int r = p * 4 + rg;
        ls[r][c] = src[(size_t)(k0 + r) * N + n0 + c];
    }
    __syncthreads();
    #pragma unroll
    for (int p = 0; p < 16; ++p) {
        int r = p * 4 + rg;
        dst[(size_t)(n0 + r) * K + k0 + c] = f2bf(ls[c][r]);
    }
}

// ---------------- GEMM: C(MxN) = A(MxK,bf16) * Bt(NxK,bf16)^T ----------------
template<int ADD_RES>
__global__ __launch_bounds__(256, 2) void gemm_bt(
    const u16* __restrict__ A, const u16* __restrict__ Bt,
    u16* __restrict__ Cb, float* __restrict__ Cf, const float* __restrict__ addend,
    int M, int N, int K)
{
    __shared__ u16 lsA[128 * 64];
    __shared__ u16 lsB[128 * 64];
    const int row0 = blockIdx.x * 128, col0 = blockIdx.y * 128;
    const int tid = threadIdx.x, wave = tid >> 6, lane = tid & 63;
    const int blk = lane >> 4, ln = lane & 15;
    const int wr = (wave >> 1) << 6, wc = (wave & 1) << 6;
    const int rstage = lane >> 3;
    const int cstage = (lane & 7) * 8;

    f32x4 acc[4][4];
    #pragma unroll
    for (int i = 0; i < 4; ++i)
        #pragma unroll
        for (int j = 0; j < 4; ++j) acc[i][j] = f32x4{0.f, 0.f, 0.f, 0.f};

    for (int k0 = 0; k0 < K; k0 += 64) {
        #pragma unroll
        for (int t = 0; t < 4; ++t) {
            int chunk = wave * 4 + t;
            int r = chunk * 8 + rstage;
            gl2lds16(A  + (size_t)(row0 + r) * K + k0 + cstage, lsA + chunk * 512);
            gl2lds16(Bt + (size_t)(col0 + r) * K + k0 + cstage, lsB + chunk * 512);
        }
        __syncthreads();
        #pragma unroll
        for (int kk = 0; kk < 2; ++kk) {
            bf16x8 af[4], bfr[4];
            #pragma unroll
            for (int i = 0; i < 4; ++i)
                af[i] = *(const bf16x8*)(lsA + (wr + i * 16 + ln) * 64 + kk * 32 + blk * 8);
            #pragma unroll
            for (int j = 0; j < 4; ++j)
                bfr[j] = *(const bf16x8*)(lsB + (wc + j * 16 + ln) * 64 + kk * 32 + blk * 8);
            #pragma unroll
            for (int i = 0; i < 4; ++i)
                #pragma unroll
                for (int j = 0; j < 4; ++j)
                    acc[i][j] = __builtin_amdgcn_mfma_f32_16x16x32_bf16(af[i], bfr[j], acc[i][j], 0, 0, 0);
        }
        __syncthreads();
    }
    #pragma unroll
    for (int i = 0; i < 4; ++i)
        #pragma unroll
        for (int j = 0; j < 4; ++j)
            #pragma unroll
            for (int r = 0; r < 4; ++r) {
                int row = row0 + wr + i * 16 + blk * 4 + r;
                int col = col0 + wc + j * 16 + ln;
                float v = acc[i][j][r];
                if (ADD_RES) {
                    Cf[(size_t)row * N + col] = v + addend[(size_t)row * N + col];
                } else {
                    Cb[(size_t)row * N + col] = f2bf(v);
                }
            }
}

// ---------------- pack QHAT / KHAT ----------------
__global__ __launch_bounds__(256) void pack_qk(
    const u16* __restrict__ QKVb, const u16* __restrict__ PEb,
    const float* __restrict__ u, const float* __restrict__ v,
    u16* __restrict__ QHAT, u16* __restrict__ KHAT)
{
    size_t idx = (size_t)blockIdx.x * 256 + threadIdx.x;
    const size_t QPART = (size_t)NHEAD * QLEN * DHEAD;
    if (idx < QPART) {
        int d = idx & 63;
        int q = (idx >> 6) & (QLEN - 1);
        int h = idx >> 17;
        float qv = bf2f(QKVb[(size_t)(MLEN + q) * (3 * DM) + h * 64 + d]);
        QHAT[((size_t)h * QLEN + q) * 128 + d]      = f2bf((qv + u[h * 64 + d]) * 0.125f);
        QHAT[((size_t)h * QLEN + q) * 128 + 64 + d] = f2bf((qv + v[h * 64 + d]) * 0.125f);
    } else {
        size_t j = idx - QPART;
        int d = j & 63;
        int k = (j >> 6) & (KLEN - 1);
        int h = j >> 18;
        KHAT[((size_t)h * KLEN + k) * 128 + d]      = QKVb[(size_t)k * (3 * DM) + DM + h * 64 + d];
        KHAT[((size_t)h * KLEN + k) * 128 + 64 + d] = PEb[(size_t)k * DM + h * 64 + d];
    }
}

// ---------------- pack VT[h][d][k] = V[k][h][d] ----------------
__global__ __launch_bounds__(256) void pack_vt(const u16* __restrict__ QKVb, u16* __restrict__ VT)
{
    __shared__ float ls[64][65];
    const int kt = blockIdx.x, h = blockIdx.y;
    const int t = threadIdx.x, c = t & 63, rg = t >> 6;
    #pragma unroll
    for (int p = 0; p < 16; ++p) {
        int r = p * 4 + rg;
        ls[r][c] = bf2f(QKVb[(size_t)(kt * 64 + r) * (3 * DM) + 2 * DM + h * 64 + c]);
    }
    __syncthreads();
    #pragma unroll
    for (int p = 0; p < 16; ++p) {
        int d = p * 4 + rg;
        VT[((size_t)h * DHEAD + d) * KLEN + kt * 64 + c] = f2bf(ls[c][d]);
    }
}

// ---------------- fused flash attention (LDS-staged, double-buffered) ----------------
// grid (QLEN/64, NHEAD), 4 waves; wave w owns q-rows qb*64+w*16 .. +15.
// K-tile (64x128) and V-tile (64d x 64k) staged via global_load_lds, XOR-swizzled
// through pre-swizzled SOURCE addresses (linear LDS dest), double-buffered.
__global__ __launch_bounds__(256, 2) void attn_fused(
    const u16* __restrict__ QHAT, const u16* __restrict__ KHAT,
    const u16* __restrict__ VT, u16* __restrict__ AVB)
{
    __shared__ u16 Kbuf[2][64 * 128];   // 2 x 16 KB
    __shared__ u16 Vbuf[2][64 * 64];    // 2 x  8 KB
    __shared__ u16 pbuf[4][16 * 64];    // 4 x  2 KB
    const int h = blockIdx.y, qb = blockIdx.x;
    const int tid = threadIdx.x;
    const int wave = tid >> 6, lane = tid & 63;
    const int blk = lane >> 4, ln = lane & 15;
    const int qrow0 = qb * 64 + wave * 16;
    u16* pb = pbuf[wave];

    const u16* kh = KHAT + (size_t)h * KLEN * 128;
    const u16* vh = VT + (size_t)h * DHEAD * KLEN;

    // staging geometry (same for every tile)
    const int ksrow = tid >> 4;                 // 0..15 within 16-row chunk
    const int kscg  = (tid & 15);               // chunk_s 0..15
    const int vsrow = tid >> 3;                 // 0..31 within 32-row chunk
    const int vscg  = (tid & 7);                // chunk_s 0..7

    auto stage = [&](int buf, int kt) {
        const int k0 = kt * 64;
        #pragma unroll
        for (int i = 0; i < 4; ++i) {
            int row = i * 16 + ksrow;
            int cg = kscg ^ (row & 7);
            gl2lds16(kh + (size_t)(k0 + row) * 128 + cg * 8,
                     &Kbuf[buf][(size_t)i * 2048 + wave * 512]);
        }
        #pragma unroll
        for (int i = 0; i < 2; ++i) {
            int row = i * 32 + vsrow;
            int cg = vscg ^ (row & 7);
            gl2lds16(vh + (size_t)row * KLEN + k0 + cg * 8,
                     &Vbuf[buf][(size_t)i * 2048 + wave * 512]);
        }
    };

    // Q' fragments: rows qrow0+ln, k-chunks of 32 (same per-lane k map as B operand)
    bf16x8 qf[4];
    const u16* qbase = QHAT + ((size_t)h * QLEN + qrow0 + ln) * 128;
    #pragma unroll
    for (int c = 0; c < 4; ++c) qf[c] = *(const bf16x8*)(qbase + c * 32 + blk * 8);

    f32x4 oacc[4];
    #pragma unroll
    for (int n = 0; n < 4; ++n) oacc[n] = f32x4{0.f, 0.f, 0.f, 0.f};
    float mi[4], li[4];
    #pragma unroll
    for (int r = 0; r < 4; ++r) { mi[r] = -1e30f; li[r] = 0.f; }

    const int nt = qb + 33;   // uniform across waves; extra tiles fully masked per wave

    // prologue: stage tile 0
    stage(0, 0);
    asm volatile("s_waitcnt vmcnt(0)" ::: "memory");
    __syncthreads();

    int cur = 0;
    for (int kt = 0; kt < nt; ++kt) {
        const int k0 = kt * 64;
        // prefetch next tile into the other buffer
        if (kt + 1 < nt) stage(cur ^ 1, kt + 1);

        // ---- QK^T from LDS (swizzled reads) ----
        f32x4 s[4];
        #pragma unroll
        for (int n = 0; n < 4; ++n) s[n] = f32x4{0.f, 0.f, 0.f, 0.f};
        #pragma unroll
        for (int n = 0; n < 4; ++n) {
            const int row = n * 16 + ln;
            #pragma unroll
            for (int c = 0; c < 4; ++c) {
                int chunk = (c * 4 + blk) ^ (ln & 7);
                bf16x8 kf = *(const bf16x8*)(&Kbuf[cur][row * 128 + chunk * 8]);
                s[n] = __builtin_amdgcn_mfma_f32_16x16x32_bf16(qf[c], kf, s[n], 0, 0, 0);
            }
        }
        // causal mask: key j allowed iff j <= q + MLEN
        if (k0 + 63 > qrow0 + MLEN) {
            #pragma unroll
            for (int n = 0; n < 4; ++n)
                #pragma unroll
                for (int r = 0; r < 4; ++r) {
                    int key = k0 + n * 16 + ln;
                    int q = qrow0 + blk * 4 + r;
                    if (key > q + MLEN) s[n][r] = -1e30f;
                }
        }
        // ---- online softmax ----
        #pragma unroll
        for (int r = 0; r < 4; ++r) {
            float mt = fmaxf(fmaxf(s[0][r], s[1][r]), fmaxf(s[2][r], s[3][r]));
            #pragma unroll
            for (int off = 1; off < 16; off <<= 1) mt = fmaxf(mt, __shfl_xor(mt, off, 64));
            float mn = fmaxf(mi[r], mt);
            float corr = __expf(mi[r] - mn);
            mi[r] = mn;
            float rs = 0.f;
            #pragma unroll
            for (int n = 0; n < 4; ++n) { float p = __expf(s[n][r] - mn); s[n][r] = p; rs += p; }
            #pragma unroll
            for (int off = 1; off < 16; off <<= 1) rs += __shfl_xor(rs, off, 64);
            li[r] = li[r] * corr + rs;
            #pragma unroll
            for (int n = 0; n < 4; ++n) oacc[n][r] *= corr;
        }
        // ---- P -> LDS (bf16, XOR-swizzled) ----
        #pragma unroll
        for (int n = 0; n < 4; ++n)
            #pragma unroll
            for (int r = 0; r < 4; ++r) {
                int row = blk * 4 + r, col = n * 16 + ln;
                int a = ((row << 6) | col) << 1;
                a ^= (row & 7) << 4;
                *(u16*)((char*)pb + a) = f2bf(s[n][r]);
            }
        asm volatile("s_waitcnt lgkmcnt(0)" ::: "memory");
        // ---- PV from LDS ----
        #pragma unroll
        for (int kk = 0; kk < 2; ++kk) {
            int a = ln * 128 + kk * 64 + blk * 16;
            a ^= (ln & 7) << 4;
            bf16x8 pf = *(const bf16x8*)((char*)pb + a);
            #pragma unroll
            for (int n = 0; n < 4; ++n) {
                const int drow = n * 16 + ln;
                int chunk = (kk * 4 + blk) ^ (ln & 7);
                bf16x8 vf = *(const bf16x8*)(&Vbuf[cur][drow * 64 + chunk * 8]);
                oacc[n] = __builtin_amdgcn_mfma_f32_16x16x32_bf16(pf, vf, oacc[n], 0, 0, 0);
            }
        }
        // next tile ready + everyone done reading cur
        asm volatile("s_waitcnt vmcnt(0)" ::: "memory");
        __syncthreads();
        cur ^= 1;
    }

    #pragma unroll
    for (int n = 0; n < 4; ++n)
        #pragma unroll
        for (int r = 0; r < 4; ++r) {
            int row = qrow0 + blk * 4 + r;
            int col = h * 64 + n * 16 + ln;
            AVB[(size_t)row * DM + col] = f2bf(oacc[n][r] / li[r]);
        }
}

// ---------------- layernorm over last dim (1024) ----------------
__global__ __launch_bounds__(256) void ln_kernel(const float* __restrict__ RES, float* __restrict__ out)
{
    const int row = blockIdx.x, t = threadIdx.x;
    const int wave = t >> 6, lane = t & 63;
    __shared__ float ws[8];
    f32x4 v = ((const f32x4*)(RES + (size_t)row * DM))[t];
    float s = v[0] + v[1] + v[2] + v[3];
    float s2 = v[0] * v[0] + v[1] * v[1] + v[2] * v[2] + v[3] * v[3];
    #pragma unroll
    for (int off = 1; off < 64; off <<= 1) {
        s += __shfl_xor(s, off, 64);
        s2 += __shfl_xor(s2, off, 64);
    }
    if (lane == 0) { ws[wave] = s; ws[4 + wave] = s2; }
    __syncthreads();
    float ts = ws[0] + ws[1] + ws[2] + ws[3];
    float ts2 = ws[4] + ws[5] + ws[6] + ws[7];
    float mu = ts * (1.f / DM);
    float var = ts2 * (1.f / DM) - mu * mu;
    float rsq = rsqrtf(var + 1e-5f);
    f32x4 o;
    #pragma unroll
    for (int c = 0; c < 4; ++c) o[c] = (v[c] - mu) * rsq;
    ((f32x4*)(out + (size_t)row * DM))[t] = o;
}

extern "C" void kernel_launch(void* const* d_in, const int* in_sizes, int n_in,
                              void* d_out, int out_size, void* d_ws, size_t ws_size,
                              hipStream_t stream)
{
    const float* hidden = (const float*)d_in[0];
    const float* pos    = (const float*)d_in[1];
    const float* u      = (const float*)d_in[2];
    const float* vv     = (const float*)d_in[3];
    const float* memory = (const float*)d_in[5];
    const float* Wqkv   = (const float*)d_in[6];
    const float* Wpe    = (const float*)d_in[7];
    const float* Wout   = (const float*)d_in[8];
    float* out = (float*)d_out;

    char* w = (char*)d_ws;
    auto alloc = [&](size_t bytes) {
        void* p = (void*)w;
        w += (bytes + 255) & ~(size_t)255;
        return p;
    };
    u16* MH    = (u16*)alloc((size_t)KLEN * DM * 2);
    u16* PEA   = (u16*)alloc((size_t)KLEN * DM * 2);
    u16* WQKVT = (u16*)alloc((size_t)3 * DM * DM * 2);
    u16* WPET  = (u16*)alloc((size_t)DM * DM * 2);
    u16* WOUTT = (u16*)alloc((size_t)DM * DM * 2);
    u16* QKVb  = (u16*)alloc((size_t)KLEN * 3 * DM * 2);
    u16* PEb   = (u16*)alloc((size_t)KLEN * DM * 2);
    u16* QHAT  = (u16*)alloc((size_t)NHEAD * QLEN * 128 * 2);
    u16* KHAT  = (u16*)alloc((size_t)NHEAD * KLEN * 128 * 2);
    u16* VTb   = (u16*)alloc((size_t)NHEAD * DHEAD * KLEN * 2);
    u16* AVB   = (u16*)alloc((size_t)QLEN * DM * 2);
    float* RES = (float*)alloc((size_t)QLEN * DM * 4);

    pack_inputs<<<8192, 256, 0, stream>>>(memory, hidden, pos, MH, PEA);
    transpose_w<<<dim3(3 * DM / 64, DM / 64), 256, 0, stream>>>(Wqkv, WQKVT, DM, 3 * DM);
    transpose_w<<<dim3(DM / 64, DM / 64), 256, 0, stream>>>(Wpe, WPET, DM, DM);
    transpose_w<<<dim3(DM / 64, DM / 64), 256, 0, stream>>>(Wout, WOUTT, DM, DM);

    gemm_bt<0><<<dim3(KLEN / 128, 3 * DM / 128), 256, 0, stream>>>(
        MH, WQKVT, QKVb, nullptr, nullptr, KLEN, 3 * DM, DM);
    gemm_bt<0><<<dim3(KLEN / 128, DM / 128), 256, 0, stream>>>(
        PEA, WPET, PEb, nullptr, nullptr, KLEN, DM, DM);

    pack_qk<<<(3u << 21) / 256, 256, 0, stream>>>(QKVb, PEb, u, vv, QHAT, KHAT);
    pack_vt<<<dim3(KLEN / 64, NHEAD), 256, 0, stream>>>(QKVb, VTb);

    attn_fused<<<dim3(QLEN / 64, NHEAD), 256, 0, stream>>>(QHAT, KHAT, VTb, AVB);

    gemm_bt<1><<<dim3(QLEN / 128, DM / 128), 256, 0, stream>>>(
        AVB, WOUTT, nullptr, RES, hidden, QLEN, DM, DM);
    ln_kernel<<<QLEN, 256, 0, stream>>>(RES, out);
}

// Round 3
// 254.250 us; speedup vs baseline: 2.1675x; 1.0210x over previous
//
#include <hip/hip_runtime.h>

typedef __attribute__((ext_vector_type(4))) float f32x4;
typedef __attribute__((ext_vector_type(8))) short bf16x8;
typedef __attribute__((ext_vector_type(4))) unsigned short u16x4;
typedef unsigned short u16;

#define DM 1024
#define NHEAD 16
#define DHEAD 64
#define QLEN 2048
#define MLEN 2048
#define KLEN 4096

__device__ __forceinline__ float bf2f(u16 u) {
    unsigned i = ((unsigned)u) << 16; float f; __builtin_memcpy(&f, &i, 4); return f;
}
__device__ __forceinline__ u16 f2bf(float f) {
    unsigned i; __builtin_memcpy(&i, &f, 4);
    unsigned r = i + 0x7fffu + ((i >> 16) & 1u);
    return (u16)(r >> 16);
}
// single-instruction f32->bf16 (RNE) via v_cvt_pk_bf16_f32, take low half
__device__ __forceinline__ u16 f2bf_hw(float f) {
    unsigned r;
    asm("v_cvt_pk_bf16_f32 %0, %1, %2" : "=v"(r) : "v"(f), "v"(f));
    return (u16)r;
}
__device__ __forceinline__ void gl2lds16(const void* g, void* l) {
    __builtin_amdgcn_global_load_lds((const __attribute__((address_space(1))) void*)g,
                                     (__attribute__((address_space(3))) void*)l, 16, 0, 0);
}

// ---------------- pack: memory||hidden -> bf16, pos -> bf16 ----------------
__global__ __launch_bounds__(256) void pack_inputs(
    const float* __restrict__ memory, const float* __restrict__ hidden,
    const float* __restrict__ pos, u16* __restrict__ MH, u16* __restrict__ PEA)
{
    size_t idx = (size_t)blockIdx.x * 256 + threadIdx.x;
    size_t e = idx * 4;
    const size_t HALF = (size_t)KLEN * DM;
    f32x4 v; u16* dst;
    if (e < HALF) {
        size_t row = e >> 10, col = e & 1023;
        const float* src = (row < MLEN) ? (memory + row * DM) : (hidden + (row - MLEN) * DM);
        v = *(const f32x4*)(src + col);
        dst = MH + e;
    } else {
        size_t e2 = e - HALF;
        v = *(const f32x4*)(pos + e2);
        dst = PEA + e2;
    }
    u16x4 o;
    #pragma unroll
    for (int c = 0; c < 4; ++c) o[c] = f2bf(v[c]);
    *(u16x4*)dst = o;
}

// ---------------- transpose f32 (K x N) -> bf16 (N x K) ----------------
__global__ __launch_bounds__(256) void transpose_w(
    const float* __restrict__ src, u16* __restrict__ dst, int K, int N)
{
    __shared__ float ls[64][65];
    const int n0 = blockIdx.x * 64, k0 = blockIdx.y * 64;
    const int t = threadIdx.x, c = t & 63, rg = t >> 6;
    #pragma unroll
    for (int p = 0; p < 16; ++p) {
        int r = p * 4 + rg;
        ls[r][c] = src[(size_t)(k0 + r) * N + n0 + c];
    }
    __syncthreads();
    #pragma unroll
    for (int p = 0; p < 16; ++p) {
        int r = p * 4 + rg;
        dst[(size_t)(n0 + r) * K + k0 + c] = f2bf(ls[c][r]);
    }
}

// ---------------- GEMM: C(MxN) = A(MxK,bf16) * Bt(NxK,bf16)^T ----------------
template<int ADD_RES>
__global__ __launch_bounds__(256, 2) void gemm_bt(
    const u16* __restrict__ A, const u16* __restrict__ Bt,
    u16* __restrict__ Cb, float* __restrict__ Cf, const float* __restrict__ addend,
    int M, int N, int K)
{
    __shared__ u16 lsA[128 * 64];
    __shared__ u16 lsB[128 * 64];
    const int row0 = blockIdx.x * 128, col0 = blockIdx.y * 128;
    const int tid = threadIdx.x, wave = tid >> 6, lane = tid & 63;
    const int blk = lane >> 4, ln = lane & 15;
    const int wr = (wave >> 1) << 6, wc = (wave & 1) << 6;
    const int rstage = lane >> 3;
    const int cstage = (lane & 7) * 8;

    f32x4 acc[4][4];
    #pragma unroll
    for (int i = 0; i < 4; ++i)
        #pragma unroll
        for (int j = 0; j < 4; ++j) acc[i][j] = f32x4{0.f, 0.f, 0.f, 0.f};

    for (int k0 = 0; k0 < K; k0 += 64) {
        #pragma unroll
        for (int t = 0; t < 4; ++t) {
            int chunk = wave * 4 + t;
            int r = chunk * 8 + rstage;
            gl2lds16(A  + (size_t)(row0 + r) * K + k0 + cstage, lsA + chunk * 512);
            gl2lds16(Bt + (size_t)(col0 + r) * K + k0 + cstage, lsB + chunk * 512);
        }
        __syncthreads();
        #pragma unroll
        for (int kk = 0; kk < 2; ++kk) {
            bf16x8 af[4], bfr[4];
            #pragma unroll
            for (int i = 0; i < 4; ++i)
                af[i] = *(const bf16x8*)(lsA + (wr + i * 16 + ln) * 64 + kk * 32 + blk * 8);
            #pragma unroll
            for (int j = 0; j < 4; ++j)
                bfr[j] = *(const bf16x8*)(lsB + (wc + j * 16 + ln) * 64 + kk * 32 + blk * 8);
            #pragma unroll
            for (int i = 0; i < 4; ++i)
                #pragma unroll
                for (int j = 0; j < 4; ++j)
                    acc[i][j] = __builtin_amdgcn_mfma_f32_16x16x32_bf16(af[i], bfr[j], acc[i][j], 0, 0, 0);
        }
        __syncthreads();
    }
    #pragma unroll
    for (int i = 0; i < 4; ++i)
        #pragma unroll
        for (int j = 0; j < 4; ++j)
            #pragma unroll
            for (int r = 0; r < 4; ++r) {
                int row = row0 + wr + i * 16 + blk * 4 + r;
                int col = col0 + wc + j * 16 + ln;
                float v = acc[i][j][r];
                if (ADD_RES) {
                    Cf[(size_t)row * N + col] = v + addend[(size_t)row * N + col];
                } else {
                    Cb[(size_t)row * N + col] = f2bf(v);
                }
            }
}

// ---------------- pack QHAT / KHAT ----------------
__global__ __launch_bounds__(256) void pack_qk(
    const u16* __restrict__ QKVb, const u16* __restrict__ PEb,
    const float* __restrict__ u, const float* __restrict__ v,
    u16* __restrict__ QHAT, u16* __restrict__ KHAT)
{
    size_t idx = (size_t)blockIdx.x * 256 + threadIdx.x;
    const size_t QPART = (size_t)NHEAD * QLEN * DHEAD;
    if (idx < QPART) {
        int d = idx & 63;
        int q = (idx >> 6) & (QLEN - 1);
        int h = idx >> 17;
        float qv = bf2f(QKVb[(size_t)(MLEN + q) * (3 * DM) + h * 64 + d]);
        QHAT[((size_t)h * QLEN + q) * 128 + d]      = f2bf((qv + u[h * 64 + d]) * 0.125f);
        QHAT[((size_t)h * QLEN + q) * 128 + 64 + d] = f2bf((qv + v[h * 64 + d]) * 0.125f);
    } else {
        size_t j = idx - QPART;
        int d = j & 63;
        int k = (j >> 6) & (KLEN - 1);
        int h = j >> 18;
        KHAT[((size_t)h * KLEN + k) * 128 + d]      = QKVb[(size_t)k * (3 * DM) + DM + h * 64 + d];
        KHAT[((size_t)h * KLEN + k) * 128 + 64 + d] = PEb[(size_t)k * DM + h * 64 + d];
    }
}

// ---------------- pack VT[h][d][k] = V[k][h][d] ----------------
__global__ __launch_bounds__(256) void pack_vt(const u16* __restrict__ QKVb, u16* __restrict__ VT)
{
    __shared__ float ls[64][65];
    const int kt = blockIdx.x, h = blockIdx.y;
    const int t = threadIdx.x, c = t & 63, rg = t >> 6;
    #pragma unroll
    for (int p = 0; p < 16; ++p) {
        int r = p * 4 + rg;
        ls[r][c] = bf2f(QKVb[(size_t)(kt * 64 + r) * (3 * DM) + 2 * DM + h * 64 + c]);
    }
    __syncthreads();
    #pragma unroll
    for (int p = 0; p < 16; ++p) {
        int d = p * 4 + rg;
        VT[((size_t)h * DHEAD + d) * KLEN + kt * 64 + c] = f2bf(ls[c][d]);
    }
}

// ---------------- fused flash attention: 8 waves, split-K halves ----------------
// grid: 512 blocks, work-balanced (qb,h) mapping. Block = 64 q-rows of one head.
// wave = g + 4*khf: g in 0..3 owns q-rows g*16..+15; khf in {0,1} owns key-half.
// Each wave keeps private online-softmax state over its key half; the two halves
// are flash-combined at the end through LDS (reusing Kbuf).
__global__ __launch_bounds__(512, 4) void attn_fused(
    const u16* __restrict__ QHAT, const u16* __restrict__ KHAT,
    const u16* __restrict__ VT, u16* __restrict__ AVB)
{
    __shared__ u16 Kbuf[2][64 * 128];   // 32 KB
    __shared__ u16 Vbuf[2][64 * 64];    // 16 KB
    __shared__ u16 pbuf[8][16 * 40];    // 10 KB (stride 40 u16 = 80 B, 16B-aligned rows)
    const int b = blockIdx.x;
    const int p = b & 255, half = b >> 8;
    const int h = p & 15;
    const int qb = half ? (15 - (p >> 4)) : (16 + (p >> 4)); // complement pairing, hard first
    const int tid = threadIdx.x;
    const int wave = tid >> 6, lane = tid & 63;
    const int g = wave & 3, khf = wave >> 2;
    const int blk = lane >> 4, ln = lane & 15;
    const int qrow0 = qb * 64 + g * 16;
    u16* pb = pbuf[wave];

    const u16* khp = KHAT + (size_t)h * KLEN * 128;
    const u16* vhp = VT + (size_t)h * DHEAD * KLEN;

    auto stage = [&](int buf, int kt) {
        const int k0 = kt * 64;
        #pragma unroll
        for (int i = 0; i < 2; ++i) {
            int c = i * 512 + tid;
            int row = c >> 4, cgl = c & 15;
            int cs = cgl ^ (row & 7);
            gl2lds16(khp + ((size_t)(k0 + row) << 7) + cs * 8,
                     &Kbuf[buf][(size_t)(i * 512 + (tid & ~63)) * 8]);
        }
        {
            int row = tid >> 3, cgl = tid & 7;
            int cs = cgl ^ (row & 7);
            gl2lds16(vhp + (size_t)row * KLEN + k0 + cs * 8,
                     &Vbuf[buf][(size_t)(tid & ~63) * 8]);
        }
    };

    // Q' fragments: rows qrow0+ln, d-chunks of 32
    bf16x8 qf[4];
    const u16* qbase = QHAT + ((size_t)h * QLEN + qrow0 + ln) * 128;
    #pragma unroll
    for (int c = 0; c < 4; ++c) qf[c] = *(const bf16x8*)(qbase + c * 32 + blk * 8);

    f32x4 oacc[4];
    #pragma unroll
    for (int n = 0; n < 4; ++n) oacc[n] = f32x4{0.f, 0.f, 0.f, 0.f};
    float mi[4], li[4];
    #pragma unroll
    for (int r = 0; r < 4; ++r) { mi[r] = -1e30f; li[r] = 0.f; }

    const int nt = qb + 33;   // uniform across all 8 waves

    stage(0, 0);
    asm volatile("s_waitcnt vmcnt(0)" ::: "memory");
    __syncthreads();

    int cur = 0;
    for (int kt = 0; kt < nt; ++kt) {
        const int k0 = kt * 64;
        if (kt + 1 < nt) stage(cur ^ 1, kt + 1);

        // ---- QK^T on this wave's 32-key half ----
        f32x4 s[2];
        #pragma unroll
        for (int n = 0; n < 2; ++n) s[n] = f32x4{0.f, 0.f, 0.f, 0.f};
        #pragma unroll
        for (int n = 0; n < 2; ++n) {
            const int krow = khf * 32 + n * 16 + ln;
            #pragma unroll
            for (int c = 0; c < 4; ++c) {
                int chunk = (c * 4 + blk) ^ (ln & 7);
                bf16x8 kf = *(const bf16x8*)(&Kbuf[cur][krow * 128 + chunk * 8]);
                s[n] = __builtin_amdgcn_mfma_f32_16x16x32_bf16(qf[c], kf, s[n], 0, 0, 0);
            }
        }
        // causal mask: key j allowed iff j <= q + MLEN
        if (k0 + khf * 32 + 31 > qrow0 + MLEN) {
            #pragma unroll
            for (int n = 0; n < 2; ++n)
                #pragma unroll
                for (int r = 0; r < 4; ++r) {
                    int key = k0 + khf * 32 + n * 16 + ln;
                    int q = qrow0 + blk * 4 + r;
                    if (key > q + MLEN) s[n][r] = -1e30f;
                }
        }
        // ---- online softmax (private per wave) ----
        float mt[4];
        #pragma unroll
        for (int r = 0; r < 4; ++r) {
            float m0 = fmaxf(s[0][r], s[1][r]);
            #pragma unroll
            for (int off = 1; off < 16; off <<= 1) m0 = fmaxf(m0, __shfl_xor(m0, off, 64));
            mt[r] = m0;
        }
        float need = fmaxf(fmaxf(mt[0] - mi[0], mt[1] - mi[1]),
                           fmaxf(mt[2] - mi[2], mt[3] - mi[3]));
        if (__all(need <= 0.f)) {
            // T13 skip: running max unchanged, no rescale
            #pragma unroll
            for (int r = 0; r < 4; ++r) {
                float rs = 0.f;
                #pragma unroll
                for (int n = 0; n < 2; ++n) { float pe = __expf(s[n][r] - mi[r]); s[n][r] = pe; rs += pe; }
                #pragma unroll
                for (int off = 1; off < 16; off <<= 1) rs += __shfl_xor(rs, off, 64);
                li[r] += rs;
            }
        } else {
            #pragma unroll
            for (int r = 0; r < 4; ++r) {
                float mn = fmaxf(mi[r], mt[r]);
                float corr = __expf(mi[r] - mn);
                mi[r] = mn;
                float rs = 0.f;
                #pragma unroll
                for (int n = 0; n < 2; ++n) { float pe = __expf(s[n][r] - mn); s[n][r] = pe; rs += pe; }
                #pragma unroll
                for (int off = 1; off < 16; off <<= 1) rs += __shfl_xor(rs, off, 64);
                li[r] = li[r] * corr + rs;
                #pragma unroll
                for (int n = 0; n < 4; ++n) oacc[n][r] *= corr;
            }
        }
        // ---- P -> wave-private LDS (stride 40) ----
        #pragma unroll
        for (int n = 0; n < 2; ++n)
            #pragma unroll
            for (int r = 0; r < 4; ++r)
                pb[(blk * 4 + r) * 40 + n * 16 + ln] = f2bf_hw(s[n][r]);
        asm volatile("s_waitcnt lgkmcnt(0)" ::: "memory");
        // ---- PV on this wave's 32-key half ----
        bf16x8 pf = *(const bf16x8*)(pb + ln * 40 + blk * 8);
        #pragma unroll
        for (int n = 0; n < 4; ++n) {
            int chunk = (khf * 4 + blk) ^ (ln & 7);
            bf16x8 vf = *(const bf16x8*)(&Vbuf[cur][(n * 16 + ln) * 64 + chunk * 8]);
            oacc[n] = __builtin_amdgcn_mfma_f32_16x16x32_bf16(pf, vf, oacc[n], 0, 0, 0);
        }

        asm volatile("s_waitcnt vmcnt(0)" ::: "memory");
        __syncthreads();
        cur ^= 1;
    }

    // ---- flash-combine the two key-halves (reuse Kbuf as f32 scratch) ----
    float* comb = (float*)&Kbuf[0][0];   // 4 g * 64 lanes * 24 f32 = 24 KB
    float* cb = comb + ((size_t)(g * 64 + lane) * 24);
    if (khf) {
        f32x4 mv, lv;
        #pragma unroll
        for (int r = 0; r < 4; ++r) { mv[r] = mi[r]; lv[r] = li[r]; }
        *(f32x4*)(cb + 0) = mv;
        *(f32x4*)(cb + 4) = lv;
        #pragma unroll
        for (int n = 0; n < 4; ++n) *(f32x4*)(cb + 8 + n * 4) = oacc[n];
    }
    __syncthreads();
    if (!khf) {
        f32x4 m2 = *(const f32x4*)(cb + 0);
        f32x4 l2 = *(const f32x4*)(cb + 4);
        f32x4 o2[4];
        #pragma unroll
        for (int n = 0; n < 4; ++n) o2[n] = *(const f32x4*)(cb + 8 + n * 4);
        #pragma unroll
        for (int r = 0; r < 4; ++r) {
            float mfull = fmaxf(mi[r], m2[r]);
            float c1 = __expf(mi[r] - mfull);
            float c2 = __expf(m2[r] - mfull);
            float inv = 1.f / (li[r] * c1 + l2[r] * c2);
            int row = qrow0 + blk * 4 + r;
            #pragma unroll
            for (int n = 0; n < 4; ++n) {
                float val = (oacc[n][r] * c1 + o2[n][r] * c2) * inv;
                AVB[(size_t)row * DM + h * 64 + n * 16 + ln] = f2bf_hw(val);
            }
        }
    }
}

// ---------------- layernorm over last dim (1024) ----------------
__global__ __launch_bounds__(256) void ln_kernel(const float* __restrict__ RES, float* __restrict__ out)
{
    const int row = blockIdx.x, t = threadIdx.x;
    const int wave = t >> 6, lane = t & 63;
    __shared__ float ws[8];
    f32x4 v = ((const f32x4*)(RES + (size_t)row * DM))[t];
    float s = v[0] + v[1] + v[2] + v[3];
    float s2 = v[0] * v[0] + v[1] * v[1] + v[2] * v[2] + v[3] * v[3];
    #pragma unroll
    for (int off = 1; off < 64; off <<= 1) {
        s += __shfl_xor(s, off, 64);
        s2 += __shfl_xor(s2, off, 64);
    }
    if (lane == 0) { ws[wave] = s; ws[4 + wave] = s2; }
    __syncthreads();
    float ts = ws[0] + ws[1] + ws[2] + ws[3];
    float ts2 = ws[4] + ws[5] + ws[6] + ws[7];
    float mu = ts * (1.f / DM);
    float var = ts2 * (1.f / DM) - mu * mu;
    float rsq = rsqrtf(var + 1e-5f);
    f32x4 o;
    #pragma unroll
    for (int c = 0; c < 4; ++c) o[c] = (v[c] - mu) * rsq;
    ((f32x4*)(out + (size_t)row * DM))[t] = o;
}

extern "C" void kernel_launch(void* const* d_in, const int* in_sizes, int n_in,
                              void* d_out, int out_size, void* d_ws, size_t ws_size,
                              hipStream_t stream)
{
    const float* hidden = (const float*)d_in[0];
    const float* pos    = (const float*)d_in[1];
    const float* u      = (const float*)d_in[2];
    const float* vv     = (const float*)d_in[3];
    const float* memory = (const float*)d_in[5];
    const float* Wqkv   = (const float*)d_in[6];
    const float* Wpe    = (const float*)d_in[7];
    const float* Wout   = (const float*)d_in[8];
    float* out = (float*)d_out;

    char* w = (char*)d_ws;
    auto alloc = [&](size_t bytes) {
        void* p = (void*)w;
        w += (bytes + 255) & ~(size_t)255;
        return p;
    };
    u16* MH    = (u16*)alloc((size_t)KLEN * DM * 2);
    u16* PEA   = (u16*)alloc((size_t)KLEN * DM * 2);
    u16* WQKVT = (u16*)alloc((size_t)3 * DM * DM * 2);
    u16* WPET  = (u16*)alloc((size_t)DM * DM * 2);
    u16* WOUTT = (u16*)alloc((size_t)DM * DM * 2);
    u16* QKVb  = (u16*)alloc((size_t)KLEN * 3 * DM * 2);
    u16* PEb   = (u16*)alloc((size_t)KLEN * DM * 2);
    u16* QHAT  = (u16*)alloc((size_t)NHEAD * QLEN * 128 * 2);
    u16* KHAT  = (u16*)alloc((size_t)NHEAD * KLEN * 128 * 2);
    u16* VTb   = (u16*)alloc((size_t)NHEAD * DHEAD * KLEN * 2);
    u16* AVB   = (u16*)alloc((size_t)QLEN * DM * 2);
    float* RES = (float*)alloc((size_t)QLEN * DM * 4);

    pack_inputs<<<8192, 256, 0, stream>>>(memory, hidden, pos, MH, PEA);
    transpose_w<<<dim3(3 * DM / 64, DM / 64), 256, 0, stream>>>(Wqkv, WQKVT, DM, 3 * DM);
    transpose_w<<<dim3(DM / 64, DM / 64), 256, 0, stream>>>(Wpe, WPET, DM, DM);
    transpose_w<<<dim3(DM / 64, DM / 64), 256, 0, stream>>>(Wout, WOUTT, DM, DM);

    gemm_bt<0><<<dim3(KLEN / 128, 3 * DM / 128), 256, 0, stream>>>(
        MH, WQKVT, QKVb, nullptr, nullptr, KLEN, 3 * DM, DM);
    gemm_bt<0><<<dim3(KLEN / 128, DM / 128), 256, 0, stream>>>(
        PEA, WPET, PEb, nullptr, nullptr, KLEN, DM, DM);

    pack_qk<<<(3u << 21) / 256, 256, 0, stream>>>(QKVb, PEb, u, vv, QHAT, KHAT);
    pack_vt<<<dim3(KLEN / 64, NHEAD), 256, 0, stream>>>(QKVb, VTb);

    attn_fused<<<dim3(512), 512, 0, stream>>>(QHAT, KHAT, VTb, AVB);

    gemm_bt<1><<<dim3(QLEN / 128, DM / 128), 256, 0, stream>>>(
        AVB, WOUTT, nullptr, RES, hidden, QLEN, DM, DM);
    ln_kernel<<<QLEN, 256, 0, stream>>>(RES, out);
}

// Round 6
// 204.571 us; speedup vs baseline: 2.6938x; 1.2428x over previous
//
#include <hip/hip_runtime.h>

typedef __attribute__((ext_vector_type(4))) float f32x4;
typedef __attribute__((ext_vector_type(16))) float f32x16;
typedef __attribute__((ext_vector_type(8))) short bf16x8;
typedef __attribute__((ext_vector_type(4))) unsigned short u16x4;
typedef unsigned short u16;

#define DM 1024
#define NHEAD 16
#define DHEAD 64
#define QLEN 2048
#define MLEN 2048
#define KLEN 4096

__device__ __forceinline__ float bf2f(u16 u) {
    unsigned i = ((unsigned)u) << 16; float f; __builtin_memcpy(&f, &i, 4); return f;
}
__device__ __forceinline__ u16 f2bf(float f) {
    unsigned i; __builtin_memcpy(&i, &f, 4);
    unsigned r = i + 0x7fffu + ((i >> 16) & 1u);
    return (u16)(r >> 16);
}
__device__ __forceinline__ unsigned cvtpk_bf16(float lo, float hi) {
    unsigned r;
    asm("v_cvt_pk_bf16_f32 %0, %1, %2" : "=v"(r) : "v"(lo), "v"(hi));
    return r;
}
__device__ __forceinline__ void gl2lds16(const void* g, void* l) {
    __builtin_amdgcn_global_load_lds((const __attribute__((address_space(1))) void*)g,
                                     (__attribute__((address_space(3))) void*)l, 16, 0, 0);
}

// ---------------- pack: memory||hidden -> bf16, pos -> bf16 ----------------
__global__ __launch_bounds__(256) void pack_inputs(
    const float* __restrict__ memory, const float* __restrict__ hidden,
    const float* __restrict__ pos, u16* __restrict__ MH, u16* __restrict__ PEA)
{
    size_t idx = (size_t)blockIdx.x * 256 + threadIdx.x;
    size_t e = idx * 4;
    const size_t HALF = (size_t)KLEN * DM;
    f32x4 v; u16* dst;
    if (e < HALF) {
        size_t row = e >> 10, col = e & 1023;
        const float* src = (row < MLEN) ? (memory + row * DM) : (hidden + (row - MLEN) * DM);
        v = *(const f32x4*)(src + col);
        dst = MH + e;
    } else {
        size_t e2 = e - HALF;
        v = *(const f32x4*)(pos + e2);
        dst = PEA + e2;
    }
    u16x4 o;
    #pragma unroll
    for (int c = 0; c < 4; ++c) o[c] = f2bf(v[c]);
    *(u16x4*)dst = o;
}

// ---------------- transpose f32 (K x N) -> bf16 (N x K) ----------------
__global__ __launch_bounds__(256) void transpose_w(
    const float* __restrict__ src, u16* __restrict__ dst, int K, int N)
{
    __shared__ float ls[64][65];
    const int n0 = blockIdx.x * 64, k0 = blockIdx.y * 64;
    const int t = threadIdx.x, c = t & 63, rg = t >> 6;
    #pragma unroll
    for (int p = 0; p < 16; ++p) {
        int r = p * 4 + rg;
        ls[r][c] = src[(size_t)(k0 + r) * N + n0 + c];
    }
    __syncthreads();
    #pragma unroll
    for (int p = 0; p < 16; ++p) {
        int r = p * 4 + rg;
        dst[(size_t)(n0 + r) * K + k0 + c] = f2bf(ls[c][r]);
    }
}

// ---------------- GEMM: C(MxN) = A(MxK,bf16) * Bt(NxK,bf16)^T ----------------
template<int ADD_RES>
__global__ __launch_bounds__(256, 2) void gemm_bt(
    const u16* __restrict__ A, const u16* __restrict__ Bt,
    u16* __restrict__ Cb, float* __restrict__ Cf, const float* __restrict__ addend,
    int M, int N, int K)
{
    __shared__ u16 lsA[128 * 64];
    __shared__ u16 lsB[128 * 64];
    const int row0 = blockIdx.x * 128, col0 = blockIdx.y * 128;
    const int tid = threadIdx.x, wave = tid >> 6, lane = tid & 63;
    const int blk = lane >> 4, ln = lane & 15;
    const int wr = (wave >> 1) << 6, wc = (wave & 1) << 6;
    const int rstage = lane >> 3;
    const int cstage = (lane & 7) * 8;

    f32x4 acc[4][4];
    #pragma unroll
    for (int i = 0; i < 4; ++i)
        #pragma unroll
        for (int j = 0; j < 4; ++j) acc[i][j] = f32x4{0.f, 0.f, 0.f, 0.f};

    for (int k0 = 0; k0 < K; k0 += 64) {
        #pragma unroll
        for (int t = 0; t < 4; ++t) {
            int chunk = wave * 4 + t;
            int r = chunk * 8 + rstage;
            gl2lds16(A  + (size_t)(row0 + r) * K + k0 + cstage, lsA + chunk * 512);
            gl2lds16(Bt + (size_t)(col0 + r) * K + k0 + cstage, lsB + chunk * 512);
        }
        __syncthreads();
        #pragma unroll
        for (int kk = 0; kk < 2; ++kk) {
            bf16x8 af[4], bfr[4];
            #pragma unroll
            for (int i = 0; i < 4; ++i)
                af[i] = *(const bf16x8*)(lsA + (wr + i * 16 + ln) * 64 + kk * 32 + blk * 8);
            #pragma unroll
            for (int j = 0; j < 4; ++j)
                bfr[j] = *(const bf16x8*)(lsB + (wc + j * 16 + ln) * 64 + kk * 32 + blk * 8);
            #pragma unroll
            for (int i = 0; i < 4; ++i)
                #pragma unroll
                for (int j = 0; j < 4; ++j)
                    acc[i][j] = __builtin_amdgcn_mfma_f32_16x16x32_bf16(af[i], bfr[j], acc[i][j], 0, 0, 0);
        }
        __syncthreads();
    }
    #pragma unroll
    for (int i = 0; i < 4; ++i)
        #pragma unroll
        for (int j = 0; j < 4; ++j)
            #pragma unroll
            for (int r = 0; r < 4; ++r) {
                int row = row0 + wr + i * 16 + blk * 4 + r;
                int col = col0 + wc + j * 16 + ln;
                float v = acc[i][j][r];
                if (ADD_RES) {
                    Cf[(size_t)row * N + col] = v + addend[(size_t)row * N + col];
                } else {
                    Cb[(size_t)row * N + col] = f2bf(v);
                }
            }
}

// ---------------- pack QHAT / KHAT ----------------
// QHAT[h][q][0:64] = (Q+u)*0.125, [64:128] = (Q+v)*0.125; KHAT = [K | pe]
__global__ __launch_bounds__(256) void pack_qk(
    const u16* __restrict__ QKVb, const u16* __restrict__ PEb,
    const float* __restrict__ u, const float* __restrict__ v,
    u16* __restrict__ QHAT, u16* __restrict__ KHAT)
{
    size_t idx = (size_t)blockIdx.x * 256 + threadIdx.x;
    const size_t QPART = (size_t)NHEAD * QLEN * DHEAD;
    if (idx < QPART) {
        int d = idx & 63;
        int q = (idx >> 6) & (QLEN - 1);
        int h = idx >> 17;
        float qv = bf2f(QKVb[(size_t)(MLEN + q) * (3 * DM) + h * 64 + d]);
        QHAT[((size_t)h * QLEN + q) * 128 + d]      = f2bf((qv + u[h * 64 + d]) * 0.125f);
        QHAT[((size_t)h * QLEN + q) * 128 + 64 + d] = f2bf((qv + v[h * 64 + d]) * 0.125f);
    } else {
        size_t j = idx - QPART;
        int d = j & 63;
        int k = (j >> 6) & (KLEN - 1);
        int h = j >> 18;
        KHAT[((size_t)h * KLEN + k) * 128 + d]      = QKVb[(size_t)k * (3 * DM) + DM + h * 64 + d];
        KHAT[((size_t)h * KLEN + k) * 128 + 64 + d] = PEb[(size_t)k * DM + h * 64 + d];
    }
}

// ---------------- pack VT[h][d][k] = V[k][h][d] ----------------
__global__ __launch_bounds__(256) void pack_vt(const u16* __restrict__ QKVb, u16* __restrict__ VT)
{
    __shared__ float ls[64][65];
    const int kt = blockIdx.x, h = blockIdx.y;
    const int t = threadIdx.x, c = t & 63, rg = t >> 6;
    #pragma unroll
    for (int p = 0; p < 16; ++p) {
        int r = p * 4 + rg;
        ls[r][c] = bf2f(QKVb[(size_t)(kt * 64 + r) * (3 * DM) + 2 * DM + h * 64 + c]);
    }
    __syncthreads();
    #pragma unroll
    for (int p = 0; p < 16; ++p) {
        int d = p * 4 + rg;
        VT[((size_t)h * DHEAD + d) * KLEN + kt * 64 + c] = f2bf(ls[c][d]);
    }
}

// ---------------- fused flash attention: 32x32 swapped-QK^T, in-register softmax ----------------
// grid 512 x 256 threads. Block = 64 q-rows of one head; 4 waves = 2 q-groups x 2 key-halves.
// Wave computes S^T = mfma(K_frag, Q_frag) so each lane owns one q-row's P values in regs.
// Row softmax: 15 local fmax + 1 shfl_xor(32). P -> LDS [q][key] (stride 40 u16, round-3-proven
// scheme) -> contiguous b128 B-frag reads (layout-proof vs contiguous-staged V).
__global__ __launch_bounds__(256, 2) void attn_fused(
    const u16* __restrict__ QHAT, const u16* __restrict__ KHAT,
    const u16* __restrict__ VT, u16* __restrict__ AVB)
{
    __shared__ u16 Kbuf[2][64 * 128];   // 32 KB (also reused as combine scratch)
    __shared__ u16 Vbuf[2][64 * 64];    // 16 KB
    __shared__ u16 pbuf[4][32 * 40];    // 10 KB: per-wave P, rows 16B-aligned
    const int b = blockIdx.x;
    const int h  = ((b & 7) << 1) | ((b >> 3) & 1);           // 2 heads per XCD -> L2-resident K/V
    const int qb = (b < 256) ? (b >> 4) : (47 - (b >> 4));    // complement pairing (cost 97/CU)
    const int tid = threadIdx.x;
    const int wave = tid >> 6, lane = tid & 63;
    const int qg = wave >> 1, khf = wave & 1;
    const int l31 = lane & 31, hi = lane >> 5;
    const int qrow0 = qb * 64 + qg * 32;
    u16* pb = pbuf[wave];

    const u16* khp = KHAT + (size_t)h * KLEN * 128;
    const u16* vhp = VT + (size_t)h * DHEAD * KLEN;

    auto stage = [&](int buf, int kt) {
        const int k0 = kt * 64;
        #pragma unroll
        for (int i = 0; i < 4; ++i) {            // K: 64 rows x 128 d, 4-bit XOR swizzle
            int row = i * 16 + (tid >> 4);
            int cs = (tid & 15) ^ (row & 15);
            gl2lds16(khp + ((size_t)(k0 + row) << 7) + cs * 8,
                     &Kbuf[buf][(size_t)(i * 4096 + (tid & ~63) * 16) / 2]);
        }
        #pragma unroll
        for (int i = 0; i < 2; ++i) {            // V^T: 64 d x 64 k, 3-bit XOR swizzle
            int row = i * 32 + (tid >> 3);
            int cs = (tid & 7) ^ (row & 7);
            gl2lds16(vhp + (size_t)row * KLEN + k0 + cs * 8,
                     &Vbuf[buf][(size_t)(i * 4096 + (tid & ~63) * 16) / 2]);
        }
    };

    // Q B-fragments (held all kernel): col q = qrow0 + l31, d-slice kd: d = kd*16 + hi*8 + {0..7}
    bf16x8 qf[8];
    {
        const u16* qbase = QHAT + ((size_t)h * QLEN + qrow0 + l31) * 128 + hi * 8;
        #pragma unroll
        for (int kd = 0; kd < 8; ++kd) qf[kd] = *(const bf16x8*)(qbase + kd * 16);
    }

    f32x16 oacc[2];
    #pragma unroll
    for (int dg = 0; dg < 2; ++dg)
        #pragma unroll
        for (int r = 0; r < 16; ++r) oacc[dg][r] = 0.f;
    float mi = -1e30f, li = 0.f;

    const int nt = qb + 33;
    const int qlim = qrow0 + 31 + MLEN;     // wave participates while its key-half start <= qlim
    const int qsel = qrow0 + l31 + MLEN;    // per-lane causal bound

    stage(0, 0);
    asm volatile("s_waitcnt vmcnt(0)" ::: "memory");
    __syncthreads();

    int cur = 0;
    for (int kt = 0; kt < nt; ++kt) {
        const int k0 = kt * 64;
        if (kt + 1 < nt) stage(cur ^ 1, kt + 1);

        if (k0 + khf * 32 <= qlim) {
            // ---- QK^T (swapped): S^T[key][q], 8 chained MFMAs over d=128 ----
            f32x16 sacc;
            #pragma unroll
            for (int r = 0; r < 16; ++r) sacc[r] = 0.f;
            const int krow = khf * 32 + l31;
            const int rx = l31 & 15;
            const u16* kb = &Kbuf[cur][0];
            #pragma unroll
            for (int kd = 0; kd < 8; ++kd) {
                int cd = (kd * 2 + hi) ^ rx;
                bf16x8 kf = *(const bf16x8*)(kb + krow * 128 + cd * 8);
                sacc = __builtin_amdgcn_mfma_f32_32x32x16_bf16(kf, qf[kd], sacc, 0, 0, 0);
            }
            // ---- causal mask (rare tiles); sacc[r] = S^T[key=crow(r,hi)][q=l31] ----
            if (k0 + khf * 32 + 31 > qrow0 + MLEN) {
                const int keyb = k0 + khf * 32 + 4 * hi;
                #pragma unroll
                for (int r = 0; r < 16; ++r) {
                    int key = keyb + (r & 3) + 8 * (r >> 2);
                    if (key > qsel) sacc[r] = -1e30f;
                }
            }
            // ---- in-register online softmax ----
            float mt = sacc[0];
            #pragma unroll
            for (int r = 1; r < 16; ++r) mt = fmaxf(mt, sacc[r]);
            mt = fmaxf(mt, __shfl_xor(mt, 32, 64));
            if (!__all(mt <= mi)) {              // T13 defer-rescale
                float mn = fmaxf(mi, mt);
                float corr = __expf(mi - mn);
                mi = mn;
                li *= corr;
                #pragma unroll
                for (int dg = 0; dg < 2; ++dg)
                    #pragma unroll
                    for (int r = 0; r < 16; ++r) oacc[dg][r] *= corr;
            }
            #pragma unroll
            for (int r = 0; r < 16; ++r) sacc[r] = __expf(sacc[r] - mi);
            float rs = sacc[0];
            #pragma unroll
            for (int r = 1; r < 16; ++r) rs += sacc[r];
            li += rs + __shfl_xor(rs, 32, 64);
            // ---- P -> LDS [q][key-within-half], dword writes ----
            // sacc[r] = key 8*(r>>2) + 4*hi + (r&3); pk word (b2,c) = keys {8b2+4hi+2c, +1}
            {
                unsigned* pd = (unsigned*)(pb + (size_t)l31 * 40);
                #pragma unroll
                for (int b2 = 0; b2 < 4; ++b2)
                    #pragma unroll
                    for (int c = 0; c < 2; ++c)
                        pd[4 * b2 + 2 * hi + c] =
                            cvtpk_bf16(sacc[4 * b2 + 2 * c], sacc[4 * b2 + 2 * c + 1]);
            }
            // ---- PV: B-frag = contiguous 8 keys per lane (matches V staging order) ----
            #pragma unroll
            for (int kkl = 0; kkl < 2; ++kkl) {
                bf16x8 pf = *(const bf16x8*)(pb + (size_t)l31 * 40 + kkl * 16 + hi * 8);
                #pragma unroll
                for (int dg = 0; dg < 2; ++dg) {
                    int vrow = dg * 32 + l31;
                    int cd = (khf * 4 + kkl * 2 + hi) ^ (vrow & 7);
                    bf16x8 vf = *(const bf16x8*)(&Vbuf[cur][vrow * 64 + cd * 8]);
                    oacc[dg] = __builtin_amdgcn_mfma_f32_32x32x16_bf16(vf, pf, oacc[dg], 0, 0, 0);
                }
            }
        }
        asm volatile("s_waitcnt vmcnt(0)" ::: "memory");
        __syncthreads();
        cur ^= 1;
    }

    // ---- flash-combine key-halves through LDS (aliased on Kbuf) ----
    float* comb = (float*)&Kbuf[0][0];            // 2 qg x 64 lanes x 36 f32 = 18 KB < 32 KB
    float* cb = comb + (size_t)(qg * 64 + lane) * 36;
    if (khf) {
        union { f32x16 v; f32x4 q4[4]; } t0, t1;
        t0.v = oacc[0]; t1.v = oacc[1];
        #pragma unroll
        for (int i = 0; i < 4; ++i) *(f32x4*)(cb + i * 4) = t0.q4[i];
        #pragma unroll
        for (int i = 0; i < 4; ++i) *(f32x4*)(cb + 16 + i * 4) = t1.q4[i];
        cb[32] = mi; cb[33] = li;
    }
    __syncthreads();
    if (!khf) {
        float m2 = cb[32], l2 = cb[33];
        float mf = fmaxf(mi, m2);
        float c1 = __expf(mi - mf), c2 = __expf(m2 - mf);
        float inv = 1.f / (li * c1 + l2 * c2);
        float a1 = c1 * inv, a2 = c2 * inv;
        unsigned* A32 = (unsigned*)AVB;
        const int q = qrow0 + l31;
        #pragma unroll
        for (int dg = 0; dg < 2; ++dg) {
            union { f32x16 v; float f[16]; } oo;
            oo.v = oacc[dg];
            #pragma unroll
            for (int b2 = 0; b2 < 4; ++b2)
                #pragma unroll
                for (int c = 0; c < 2; ++c) {
                    float lo  = oo.f[4 * b2 + 2 * c]     * a1 + cb[dg * 16 + 4 * b2 + 2 * c]     * a2;
                    float hi2 = oo.f[4 * b2 + 2 * c + 1] * a1 + cb[dg * 16 + 4 * b2 + 2 * c + 1] * a2;
                    A32[(size_t)q * (DM / 2) + h * 32 + dg * 16 + 4 * b2 + 2 * hi + c] = cvtpk_bf16(lo, hi2);
                }
        }
    }
}

// ---------------- layernorm over last dim (1024) ----------------
__global__ __launch_bounds__(256) void ln_kernel(const float* __restrict__ RES, float* __restrict__ out)
{
    const int row = blockIdx.x, t = threadIdx.x;
    const int wave = t >> 6, lane = t & 63;
    __shared__ float ws[8];
    f32x4 v = ((const f32x4*)(RES + (size_t)row * DM))[t];
    float s = v[0] + v[1] + v[2] + v[3];
    float s2 = v[0] * v[0] + v[1] * v[1] + v[2] * v[2] + v[3] * v[3];
    #pragma unroll
    for (int off = 1; off < 64; off <<= 1) {
        s += __shfl_xor(s, off, 64);
        s2 += __shfl_xor(s2, off, 64);
    }
    if (lane == 0) { ws[wave] = s; ws[4 + wave] = s2; }
    __syncthreads();
    float ts = ws[0] + ws[1] + ws[2] + ws[3];
    float ts2 = ws[4] + ws[5] + ws[6] + ws[7];
    float mu = ts * (1.f / DM);
    float var = ts2 * (1.f / DM) - mu * mu;
    float rsq = rsqrtf(var + 1e-5f);
    f32x4 o;
    #pragma unroll
    for (int c = 0; c < 4; ++c) o[c] = (v[c] - mu) * rsq;
    ((f32x4*)(out + (size_t)row * DM))[t] = o;
}

extern "C" void kernel_launch(void* const* d_in, const int* in_sizes, int n_in,
                              void* d_out, int out_size, void* d_ws, size_t ws_size,
                              hipStream_t stream)
{
    const float* hidden = (const float*)d_in[0];
    const float* pos    = (const float*)d_in[1];
    const float* u      = (const float*)d_in[2];
    const float* vv     = (const float*)d_in[3];
    const float* memory = (const float*)d_in[5];
    const float* Wqkv   = (const float*)d_in[6];
    const float* Wpe    = (const float*)d_in[7];
    const float* Wout   = (const float*)d_in[8];
    float* out = (float*)d_out;

    char* w = (char*)d_ws;
    auto alloc = [&](size_t bytes) {
        void* p = (void*)w;
        w += (bytes + 255) & ~(size_t)255;
        return p;
    };
    u16* MH    = (u16*)alloc((size_t)KLEN * DM * 2);
    u16* PEA   = (u16*)alloc((size_t)KLEN * DM * 2);
    u16* WQKVT = (u16*)alloc((size_t)3 * DM * DM * 2);
    u16* WPET  = (u16*)alloc((size_t)DM * DM * 2);
    u16* WOUTT = (u16*)alloc((size_t)DM * DM * 2);
    u16* QKVb  = (u16*)alloc((size_t)KLEN * 3 * DM * 2);
    u16* PEb   = (u16*)alloc((size_t)KLEN * DM * 2);
    u16* QHAT  = (u16*)alloc((size_t)NHEAD * QLEN * 128 * 2);
    u16* KHAT  = (u16*)alloc((size_t)NHEAD * KLEN * 128 * 2);
    u16* VTb   = (u16*)alloc((size_t)NHEAD * DHEAD * KLEN * 2);
    u16* AVB   = (u16*)alloc((size_t)QLEN * DM * 2);
    float* RES = (float*)alloc((size_t)QLEN * DM * 4);

    pack_inputs<<<8192, 256, 0, stream>>>(memory, hidden, pos, MH, PEA);
    transpose_w<<<dim3(3 * DM / 64, DM / 64), 256, 0, stream>>>(Wqkv, WQKVT, DM, 3 * DM);
    transpose_w<<<dim3(DM / 64, DM / 64), 256, 0, stream>>>(Wpe, WPET, DM, DM);
    transpose_w<<<dim3(DM / 64, DM / 64), 256, 0, stream>>>(Wout, WOUTT, DM, DM);

    gemm_bt<0><<<dim3(KLEN / 128, 3 * DM / 128), 256, 0, stream>>>(
        MH, WQKVT, QKVb, nullptr, nullptr, KLEN, 3 * DM, DM);
    gemm_bt<0><<<dim3(KLEN / 128, DM / 128), 256, 0, stream>>>(
        PEA, WPET, PEb, nullptr, nullptr, KLEN, DM, DM);

    pack_qk<<<(3u << 21) / 256, 256, 0, stream>>>(QKVb, PEb, u, vv, QHAT, KHAT);
    pack_vt<<<dim3(KLEN / 64, NHEAD), 256, 0, stream>>>(QKVb, VTb);

    attn_fused<<<dim3(512), 256, 0, stream>>>(QHAT, KHAT, VTb, AVB);

    gemm_bt<1><<<dim3(QLEN / 128, DM / 128), 256, 0, stream>>>(
        AVB, WOUTT, nullptr, RES, hidden, QLEN, DM, DM);
    ln_kernel<<<QLEN, 256, 0, stream>>>(RES, out);
}